// Round 3
// baseline (144.069 us; speedup 1.0000x reference)
//
#include <hip/hip_runtime.h>
#include <math.h>

constexpr int NN = 32768;   // nodes
constexpr int SS = 32768;   // subgraph-node entries
constexpr int CC = 1024;    // clusters
constexpr int EE = 16384;   // coarsen edges
constexpr int BB = 16;      // graphs
constexpr int PP = 64;      // patches per graph
constexpr int NC = 10;      // classes

__device__ __forceinline__ float rdlane(float v, int l) {
    return __int_as_float(__builtin_amdgcn_readlane(__float_as_int(v), l));
}

// ---------------------------------------------------------------------------
// Fused per-node dense chain (6 GEMM phases on a 64x64 tile):
//   t1 = relu(x@W1+b1); h = relu(t1@W2+b2);
//   u  = relu(h@Wp1+bp1); Qpre = u@Wp2+bp2; K = h@WK+bK; V = h@WV+bV
// Block: 128 threads = 16(tx: 4 cols) x 8(ty: 8 rows); acc 8x4 per thread.
// A-tiles transposed [k][row] stride 68; W [k][col] stride 68.
// ---------------------------------------------------------------------------
#define TS 68

__device__ __forceinline__ void gemm84(const float* A, const float* W,
                                       const float* __restrict__ bias,
                                       int r0, int c0, float acc[8][4])
{
#pragma unroll
    for (int dc = 0; dc < 4; ++dc) {
        float bv = bias[c0 + dc];
#pragma unroll
        for (int dr = 0; dr < 8; ++dr) acc[dr][dc] = bv;
    }
#pragma unroll 8
    for (int k = 0; k < 64; ++k) {
        float4 a0 = *(const float4*)(A + k * TS + r0);
        float4 a1 = *(const float4*)(A + k * TS + r0 + 4);
        float4 wv = *(const float4*)(W + k * TS + c0);
        float ar[8] = {a0.x, a0.y, a0.z, a0.w, a1.x, a1.y, a1.z, a1.w};
        float wr[4] = {wv.x, wv.y, wv.z, wv.w};
#pragma unroll
        for (int dr = 0; dr < 8; ++dr)
#pragma unroll
            for (int dc = 0; dc < 4; ++dc)
                acc[dr][dc] = fmaf(ar[dr], wr[dc], acc[dr][dc]);
    }
}

__device__ __forceinline__ void stageW(float* dst, const float* __restrict__ src, int tid)
{
#pragma unroll
    for (int t = 0; t < 32; ++t) {
        int idx = tid + t * 128;
        dst[(idx >> 6) * TS + (idx & 63)] = src[idx];
    }
}

__device__ __forceinline__ void outT_relu(float* dst, int r0, int c0, float acc[8][4])
{
#pragma unroll
    for (int dc = 0; dc < 4; ++dc) {
        *(float4*)(dst + (c0 + dc) * TS + r0) =
            make_float4(fmaxf(acc[0][dc], 0.f), fmaxf(acc[1][dc], 0.f),
                        fmaxf(acc[2][dc], 0.f), fmaxf(acc[3][dc], 0.f));
        *(float4*)(dst + (c0 + dc) * TS + r0 + 4) =
            make_float4(fmaxf(acc[4][dc], 0.f), fmaxf(acc[5][dc], 0.f),
                        fmaxf(acc[6][dc], 0.f), fmaxf(acc[7][dc], 0.f));
    }
}

__device__ __forceinline__ void outG(float* __restrict__ dst, size_t rowbase,
                                     int r0, int c0, float acc[8][4])
{
#pragma unroll
    for (int dr = 0; dr < 8; ++dr)
        *(float4*)(dst + (rowbase + r0 + dr) * 64 + c0) =
            make_float4(acc[dr][0], acc[dr][1], acc[dr][2], acc[dr][3]);
}

__global__ __launch_bounds__(128) void k_node(
    const float* __restrict__ x,
    const float* __restrict__ W1, const float* __restrict__ b1,
    const float* __restrict__ W2, const float* __restrict__ b2,
    const float* __restrict__ Wp1, const float* __restrict__ bp1,
    const float* __restrict__ Wp2, const float* __restrict__ bp2,
    const float* __restrict__ WK, const float* __restrict__ bK,
    const float* __restrict__ WV, const float* __restrict__ bV,
    float* __restrict__ Qpre, float* __restrict__ Kf, float* __restrict__ Vf)
{
    __shared__ __align__(16) float bufA[64 * TS];
    __shared__ __align__(16) float bufB[64 * TS];
    __shared__ __align__(16) float wlds[64 * TS];
    int tid = threadIdx.x;
    int tx = tid & 15, ty = tid >> 4;
    int r0 = ty * 8, c0 = tx * 4;
    size_t rowbase = (size_t)blockIdx.x * 64;
    const float* xb = x + rowbase * 64;
#pragma unroll
    for (int t = 0; t < 32; ++t) {
        int idx = tid + t * 128;
        bufA[(idx & 63) * TS + (idx >> 6)] = xb[idx];
    }
    stageW(wlds, W1, tid);
    __syncthreads();
    float acc[8][4];
    // phase 0: t1 = relu(x@W1+b1) -> bufB
    gemm84(bufA, wlds, b1, r0, c0, acc);
    outT_relu(bufB, r0, c0, acc);
    __syncthreads();
    stageW(wlds, W2, tid);
    __syncthreads();
    // phase 1: h = relu(t1@W2+b2) -> bufA
    gemm84(bufB, wlds, b2, r0, c0, acc);
    outT_relu(bufA, r0, c0, acc);
    __syncthreads();
    stageW(wlds, Wp1, tid);
    __syncthreads();
    // phase 2: u = relu(h@Wp1+bp1) -> bufB
    gemm84(bufA, wlds, bp1, r0, c0, acc);
    outT_relu(bufB, r0, c0, acc);
    __syncthreads();
    stageW(wlds, Wp2, tid);
    __syncthreads();
    // phase 3: Qpre = u@Wp2+bp2 -> global
    gemm84(bufB, wlds, bp2, r0, c0, acc);
    outG(Qpre, rowbase, r0, c0, acc);
    __syncthreads();
    stageW(wlds, WK, tid);
    __syncthreads();
    // phase 4: K = h@WK+bK -> global
    gemm84(bufA, wlds, bK, r0, c0, acc);
    outG(Kf, rowbase, r0, c0, acc);
    __syncthreads();
    stageW(wlds, WV, tid);
    __syncthreads();
    // phase 5: V = h@WV+bV -> global
    gemm84(bufA, wlds, bV, r0, c0, acc);
    outG(Vf, rowbase, r0, c0, acc);
}

// ---------------------------------------------------------------------------
__global__ void k_prep1(const int* __restrict__ row, const float* __restrict__ attr,
                        float* __restrict__ deg, int* __restrict__ rowcnt, int E)
{
    int e = blockIdx.x * 256 + threadIdx.x;
    if (e < E) {
        int r = row[e];
        atomicAdd(&deg[r], attr[e]);
        atomicAdd(&rowcnt[r], 1);
    }
}

__global__ __launch_bounds__(1024) void k_scan(
    const int* __restrict__ rowcnt, int* __restrict__ rowptr, int* __restrict__ rowfill,
    const int* __restrict__ batch, int* __restrict__ segoff)
{
    __shared__ int buf[1024];
    int tid = threadIdx.x;
    int v = rowcnt[tid];
    buf[tid] = v;
    __syncthreads();
    for (int off = 1; off < 1024; off <<= 1) {
        int t = (tid >= off) ? buf[tid - off] : 0;
        __syncthreads();
        buf[tid] += t;
        __syncthreads();
    }
    int incl = buf[tid];
    if (tid == 0) rowptr[0] = 0;
    rowptr[tid + 1] = incl;
    rowfill[tid] = incl - v;
    int lo = 0, hi = SS;
    while (lo < hi) { int mid = (lo + hi) >> 1; if (batch[mid] < tid) lo = mid + 1; else hi = mid; }
    segoff[tid] = lo;
    if (tid == 0) segoff[CC] = SS;
}

__global__ void k_prep2(const int* __restrict__ row, const int* __restrict__ col,
                        const float* __restrict__ attr, const float* __restrict__ deg,
                        float* __restrict__ eaw, int* __restrict__ rowfill,
                        int* __restrict__ eidx, int E)
{
    int e = blockIdx.x * 256 + threadIdx.x;
    if (e < E) {
        int r = row[e];
        float dr = deg[r], dc = deg[col[e]];
        float ir = dr > 0.f ? 1.f / sqrtf(dr) : 0.f;
        float ic = dc > 0.f ? 1.f / sqrtf(dc) : 0.f;
        eaw[e] = ir * attr[e] * ic;
        int pos = atomicAdd(&rowfill[r], 1);
        eidx[pos] = e;
    }
}

// ---------------------------------------------------------------------------
// Per-cluster Q-sum + post-deepset MLP -> Qk (relu'd)
// 4 waves split entries; wave 0 reduces + runs the MLP.
// ---------------------------------------------------------------------------
__global__ __launch_bounds__(256) void k_qk(
    const float* __restrict__ Qpre, const int* __restrict__ mapper,
    const int* __restrict__ segoff,
    const float* __restrict__ Wpo1, const float* __restrict__ bpo1,
    const float* __restrict__ Wpo2, const float* __restrict__ bpo2,
    float* __restrict__ Qk)
{
    __shared__ float part[4][64];
    int c = blockIdx.x;
    int tid = threadIdx.x, j = tid & 63, g = tid >> 6;
    int s0 = segoff[c], s1 = segoff[c + 1];
    float qs = 0.f;
    for (int s = s0 + g; s < s1; s += 4)
        qs += Qpre[(size_t)mapper[s] * 64 + j];
    part[g][j] = qs;
    __syncthreads();
    if (g == 0) {
        qs = part[0][j] + part[1][j] + part[2][j] + part[3][j];
        float a1 = bpo1[j];
#pragma unroll
        for (int i = 0; i < 64; ++i) a1 = fmaf(rdlane(qs, i), Wpo1[i * 64 + j], a1);
        float t = fmaxf(a1, 0.f);
        float a2 = bpo2[j];
#pragma unroll
        for (int i = 0; i < 64; ++i) a2 = fmaf(rdlane(t, i), Wpo2[i * 64 + j], a2);
        Qk[c * 64 + j] = fmaxf(a2, 0.f);
    }
}

// ---------------------------------------------------------------------------
// Fused Msb-build + edge scatter. Block per source cluster r, 4 waves.
// Wave g holds Msb rows [16g,16g+16) in registers; every wave walks all
// entries, so each wave owns the complete ks/krs/vs sums (no LDS).
// Per out-edge e=(r->c):
//   wave g: wj = sum_{i in rows} Qk[c][i]*msb[i]  -> atomic H[c][j] += w*sb2*wj
//   wave 0 additionally: p1=Qk[c].Ksk[r], p2=Qk[c].Krsum[r] (shfl reduce),
//     H[c][j] += w*sa2*p1*Vsum[r][j];  den[c] += w*(sa2*L_r*p1 + sb2*p2)
// ---------------------------------------------------------------------------
__global__ __launch_bounds__(256) void k_msb_edges(
    const float* __restrict__ Kf, const float* __restrict__ Vf,
    const int* __restrict__ mapper, const int* __restrict__ segoff,
    const float* __restrict__ Qk, const float* __restrict__ eaw,
    const int* __restrict__ col, const int* __restrict__ rowptr,
    const int* __restrict__ eidx, const float* __restrict__ ab,
    float* __restrict__ H, float* __restrict__ den)
{
    int r = blockIdx.x;
    int e0 = rowptr[r], e1 = rowptr[r + 1];
    if (e0 == e1) return;   // nothing downstream consumes this block's work
    int tid = threadIdx.x, j = tid & 63, g = tid >> 6;
    int base = g * 16;
    int s0 = segoff[r], s1 = segoff[r + 1];
    float msb[16];
#pragma unroll
    for (int i = 0; i < 16; ++i) msb[i] = 0.f;
    float ks = 0.f, krs = 0.f, vs = 0.f;
    if (s0 < s1) {
        int m = mapper[s0];
        float kj = Kf[(size_t)m * 64 + j];
        float vj = Vf[(size_t)m * 64 + j];
        for (int s = s0; s < s1; ++s) {
            float kjc = kj, vjc = vj;
            if (s + 1 < s1) {
                int m2 = mapper[s + 1];
                kj = Kf[(size_t)m2 * 64 + j];
                vj = Vf[(size_t)m2 * 64 + j];
            }
            float kr = fmaxf(kjc, 0.f);
            ks += kjc; krs += kr; vs += vjc;
#pragma unroll
            for (int i = 0; i < 16; ++i)
                msb[i] = fmaf(rdlane(kr, base + i), vjc, msb[i]);
        }
    }
    int L = s1 - s0;
    float Lr = (float)L;
    float Lm = (float)(L > 0 ? L : 1);
    float kskj = fmaxf(ks / Lm, 0.f);
    float krj = krs;
    float vsj = vs;
    float a0 = ab[0], a1 = ab[1];
    float sa2 = 1.f + expf(a1 - a0);   // 1/softmax0
    float sb2 = 1.f + expf(a0 - a1);   // 1/softmax1

    int e = eidx[e0];
    int c = col[e];
    float w = eaw[e];
    float qv = Qk[c * 64 + j];
    for (int idx = e0; idx < e1; ++idx) {
        int cc = c; float wc = w, qc = qv;
        if (idx + 1 < e1) {
            int e2 = eidx[idx + 1];
            c = col[e2];
            w = eaw[e2];
            qv = Qk[c * 64 + j];
        }
        float wj = 0.f;
#pragma unroll
        for (int i = 0; i < 16; ++i) wj = fmaf(rdlane(qc, base + i), msb[i], wj);
        if (g == 0) {
            float p1 = qc * kskj;
            float p2 = qc * krj;
#pragma unroll
            for (int o = 32; o > 0; o >>= 1) { p1 += __shfl_xor(p1, o); p2 += __shfl_xor(p2, o); }
            atomicAdd(&H[cc * 64 + j], wc * (sb2 * wj + sa2 * p1 * vsj));
            if (j == 0) atomicAdd(&den[cc], wc * (sa2 * Lr * p1 + sb2 * p2));
        } else {
            atomicAdd(&H[cc * 64 + j], wc * sb2 * wj);
        }
    }
}

// ---------------------------------------------------------------------------
__global__ __launch_bounds__(64) void k_final(
    const float* __restrict__ H, const float* __restrict__ den,
    const float* __restrict__ Wc1, const float* __restrict__ bc1,
    const float* __restrict__ Wc2, const float* __restrict__ bc2,
    float* __restrict__ out)
{
    int bg = blockIdx.x;
    int j = threadIdx.x;
    float acc = 0.f;
    for (int p = 0; p < PP; ++p) {
        int c = bg * PP + p;
        acc += H[c * 64 + j] / (den[c] + 1e-6f);
    }
    float g = acc * (1.f / (float)PP);
    int m = j & 31;
    float a1 = bc1[m];
#pragma unroll
    for (int i = 0; i < 64; ++i) a1 = fmaf(rdlane(g, i), Wc1[i * 32 + m], a1);
    float c1 = fmaxf(a1, 0.f);
    int n = (j < NC) ? j : 0;
    float a2 = bc2[n];
#pragma unroll
    for (int i = 0; i < 32; ++i) a2 = fmaf(rdlane(c1, i), Wc2[i * NC + n], a2);
    if (j < NC) out[bg * NC + j] = a2;
}

// ---------------------------------------------------------------------------
extern "C" void kernel_launch(void* const* d_in, const int* in_sizes, int n_in,
                              void* d_out, int out_size, void* d_ws, size_t ws_size,
                              hipStream_t stream)
{
    const float* x      = (const float*)d_in[0];
    const int*   mapper = (const int*)d_in[1];
    const int*   batch  = (const int*)d_in[2];
    const int*   row    = (const int*)d_in[3];
    const int*   col    = (const int*)d_in[4];
    const float* attr   = (const float*)d_in[5];
    const float* W_in1  = (const float*)d_in[6];
    const float* b_in1  = (const float*)d_in[7];
    const float* W_in2  = (const float*)d_in[8];
    const float* b_in2  = (const float*)d_in[9];
    const float* W_pre1 = (const float*)d_in[10];
    const float* b_pre1 = (const float*)d_in[11];
    const float* W_pre2 = (const float*)d_in[12];
    const float* b_pre2 = (const float*)d_in[13];
    const float* W_post1= (const float*)d_in[14];
    const float* b_post1= (const float*)d_in[15];
    const float* W_post2= (const float*)d_in[16];
    const float* b_post2= (const float*)d_in[17];
    const float* W_K    = (const float*)d_in[18];
    const float* b_K    = (const float*)d_in[19];
    const float* W_V    = (const float*)d_in[20];
    const float* b_V    = (const float*)d_in[21];
    const float* alpha_beta = (const float*)d_in[22];
    const float* W_c1   = (const float*)d_in[23];
    const float* b_c1   = (const float*)d_in[24];
    const float* W_c2   = (const float*)d_in[25];
    const float* b_c2   = (const float*)d_in[26];

    float* ws = (float*)d_ws;
    float* Qpre  = ws;                        // N*64
    float* Kf    = Qpre  + (size_t)NN * 64;
    float* Vf    = Kf    + (size_t)NN * 64;
    float* Qk    = Vf    + (size_t)NN * 64;   // C*64
    float* eaw   = Qk    + (size_t)CC * 64;   // E
    // --- zeroed region (contiguous) ---
    float* H     = eaw   + (size_t)EE;        // C*64
    float* den   = H     + (size_t)CC * 64;   // C
    float* deg   = den   + (size_t)CC;        // C
    int*  rowcnt = (int*)(deg + (size_t)CC);  // C
    // --- end zeroed region ---
    int*  segoff = rowcnt + CC;               // C+1
    int*  rowptr = segoff + (CC + 1);         // C+1
    int*  rowfill= rowptr + (CC + 1);         // C
    int*  eidx   = rowfill+ (CC + 1);         // E

    size_t zero_bytes = ((size_t)CC * 64 + CC + CC + CC) * sizeof(float);
    hipMemsetAsync(H, 0, zero_bytes, stream);

    k_prep1<<<EE / 256, 256, 0, stream>>>(row, attr, deg, rowcnt, EE);
    k_scan<<<1, 1024, 0, stream>>>(rowcnt, rowptr, rowfill, batch, segoff);
    k_prep2<<<EE / 256, 256, 0, stream>>>(row, col, attr, deg, eaw, rowfill, eidx, EE);
    k_node<<<NN / 64, 128, 0, stream>>>(x, W_in1, b_in1, W_in2, b_in2,
                                        W_pre1, b_pre1, W_pre2, b_pre2,
                                        W_K, b_K, W_V, b_V, Qpre, Kf, Vf);
    k_qk<<<CC, 256, 0, stream>>>(Qpre, mapper, segoff,
                                 W_post1, b_post1, W_post2, b_post2, Qk);
    k_msb_edges<<<CC, 256, 0, stream>>>(Kf, Vf, mapper, segoff, Qk, eaw, col,
                                        rowptr, eidx, alpha_beta, H, den);
    k_final<<<BB, 64, 0, stream>>>(H, den, W_c1, b_c1, W_c2, b_c2, (float*)d_out);
}

// Round 4
// 142.475 us; speedup vs baseline: 1.0112x; 1.0112x over previous
//
#include <hip/hip_runtime.h>
#include <math.h>

constexpr int NN = 32768;   // nodes
constexpr int SS = 32768;   // subgraph-node entries
constexpr int CC = 1024;    // clusters
constexpr int EE = 16384;   // coarsen edges
constexpr int BB = 16;      // graphs
constexpr int PP = 64;      // patches per graph
constexpr int NC = 10;      // classes

__device__ __forceinline__ float rdlane(float v, int l) {
    return __int_as_float(__builtin_amdgcn_readlane(__float_as_int(v), l));
}

// ---------------------------------------------------------------------------
// k_node: fused per-node dense chain, 5 GEMM phases on a 64x64 row tile:
//   t1 = relu(x@W1+b1); h = relu(t1@W2+b2); u = relu(h@Wp1+bp1)  -> u (global)
//   K = h@WK+bK -> KV[:,0:64];  V = h@WV+bV -> KV[:,64:128]
// (Wp2 is applied later in k_qk via linearity: Qs = (sum u)@Wp2 + L*bp2.)
// 256 threads = 16x16, 4x4 acc per thread. LDS tiles transposed, stride 68.
// ---------------------------------------------------------------------------
#define TS 68

__device__ __forceinline__ void gemm64(const float* A, const float* W,
                                       const float* __restrict__ bias,
                                       int r0, int c0, float acc[4][4])
{
#pragma unroll
    for (int dc = 0; dc < 4; ++dc) {
        float bv = bias[c0 + dc];
        acc[0][dc] = bv; acc[1][dc] = bv; acc[2][dc] = bv; acc[3][dc] = bv;
    }
#pragma unroll 16
    for (int k = 0; k < 64; ++k) {
        float4 av = *(const float4*)(A + k * TS + r0);
        float4 wv = *(const float4*)(W + k * TS + c0);
        acc[0][0] = fmaf(av.x, wv.x, acc[0][0]); acc[0][1] = fmaf(av.x, wv.y, acc[0][1]);
        acc[0][2] = fmaf(av.x, wv.z, acc[0][2]); acc[0][3] = fmaf(av.x, wv.w, acc[0][3]);
        acc[1][0] = fmaf(av.y, wv.x, acc[1][0]); acc[1][1] = fmaf(av.y, wv.y, acc[1][1]);
        acc[1][2] = fmaf(av.y, wv.z, acc[1][2]); acc[1][3] = fmaf(av.y, wv.w, acc[1][3]);
        acc[2][0] = fmaf(av.z, wv.x, acc[2][0]); acc[2][1] = fmaf(av.z, wv.y, acc[2][1]);
        acc[2][2] = fmaf(av.z, wv.z, acc[2][2]); acc[2][3] = fmaf(av.z, wv.w, acc[2][3]);
        acc[3][0] = fmaf(av.w, wv.x, acc[3][0]); acc[3][1] = fmaf(av.w, wv.y, acc[3][1]);
        acc[3][2] = fmaf(av.w, wv.z, acc[3][2]); acc[3][3] = fmaf(av.w, wv.w, acc[3][3]);
    }
}

__device__ __forceinline__ void stageW(float* dst, const float* __restrict__ src, int tid)
{
#pragma unroll
    for (int t = 0; t < 16; ++t) {
        int idx = tid + t * 256;
        dst[(idx >> 6) * TS + (idx & 63)] = src[idx];
    }
}

__device__ __forceinline__ void outT_relu(float* dst, int r0, int c0, float acc[4][4])
{
#pragma unroll
    for (int dc = 0; dc < 4; ++dc) {
        *(float4*)(dst + (c0 + dc) * TS + r0) =
            make_float4(fmaxf(acc[0][dc], 0.f), fmaxf(acc[1][dc], 0.f),
                        fmaxf(acc[2][dc], 0.f), fmaxf(acc[3][dc], 0.f));
    }
}

__device__ __forceinline__ void outG2(float* __restrict__ dst, size_t rowbase, int ld,
                                      int off, int r0, int c0, float acc[4][4], bool dorelu)
{
#pragma unroll
    for (int dr = 0; dr < 4; ++dr) {
        float4 v = make_float4(acc[dr][0], acc[dr][1], acc[dr][2], acc[dr][3]);
        if (dorelu) {
            v.x = fmaxf(v.x, 0.f); v.y = fmaxf(v.y, 0.f);
            v.z = fmaxf(v.z, 0.f); v.w = fmaxf(v.w, 0.f);
        }
        *(float4*)(dst + (rowbase + r0 + dr) * ld + off + c0) = v;
    }
}

__global__ __launch_bounds__(256) void k_node(
    const float* __restrict__ x,
    const float* __restrict__ W1, const float* __restrict__ b1,
    const float* __restrict__ W2, const float* __restrict__ b2,
    const float* __restrict__ Wp1, const float* __restrict__ bp1,
    const float* __restrict__ WK, const float* __restrict__ bK,
    const float* __restrict__ WV, const float* __restrict__ bV,
    float* __restrict__ u, float* __restrict__ KV)
{
    __shared__ __align__(16) float bufA[64 * TS];
    __shared__ __align__(16) float bufB[64 * TS];
    __shared__ __align__(16) float wlds[64 * TS];
    int tid = threadIdx.x;
    int tx = tid & 15, ty = tid >> 4;
    int r0 = ty * 4, c0 = tx * 4;
    size_t rowbase = (size_t)blockIdx.x * 64;
    const float* xb = x + rowbase * 64;
#pragma unroll
    for (int t = 0; t < 16; ++t) {
        int idx = tid + t * 256;
        bufA[(idx & 63) * TS + (idx >> 6)] = xb[idx];
    }
    stageW(wlds, W1, tid);
    __syncthreads();
    float acc[4][4];
    // t1 = relu(x@W1+b1) -> bufB
    gemm64(bufA, wlds, b1, r0, c0, acc);
    outT_relu(bufB, r0, c0, acc);
    __syncthreads();
    stageW(wlds, W2, tid);
    __syncthreads();
    // h = relu(t1@W2+b2) -> bufA
    gemm64(bufB, wlds, b2, r0, c0, acc);
    outT_relu(bufA, r0, c0, acc);
    __syncthreads();
    stageW(wlds, Wp1, tid);
    __syncthreads();
    // u = relu(h@Wp1+bp1) -> global
    gemm64(bufA, wlds, bp1, r0, c0, acc);
    outG2(u, rowbase, 64, 0, r0, c0, acc, true);
    __syncthreads();
    stageW(wlds, WK, tid);
    __syncthreads();
    // K = h@WK+bK -> KV[:,0:64]
    gemm64(bufA, wlds, bK, r0, c0, acc);
    outG2(KV, rowbase, 128, 0, r0, c0, acc, false);
    __syncthreads();
    stageW(wlds, WV, tid);
    __syncthreads();
    // V = h@WV+bV -> KV[:,64:128]
    gemm64(bufA, wlds, bV, r0, c0, acc);
    outG2(KV, rowbase, 128, 64, r0, c0, acc, false);
}

// ---------------------------------------------------------------------------
__global__ void k_prep1(const int* __restrict__ row, const float* __restrict__ attr,
                        float* __restrict__ deg, int* __restrict__ rowcnt, int E)
{
    int e = blockIdx.x * 256 + threadIdx.x;
    if (e < E) {
        int r = row[e];
        atomicAdd(&deg[r], attr[e]);
        atomicAdd(&rowcnt[r], 1);
    }
}

__global__ __launch_bounds__(1024) void k_scan(
    const int* __restrict__ rowcnt, int* __restrict__ rowptr, int* __restrict__ rowfill,
    const int* __restrict__ batch, int* __restrict__ segoff)
{
    __shared__ int buf[1024];
    int tid = threadIdx.x;
    int v = rowcnt[tid];
    buf[tid] = v;
    __syncthreads();
    for (int off = 1; off < 1024; off <<= 1) {
        int t = (tid >= off) ? buf[tid - off] : 0;
        __syncthreads();
        buf[tid] += t;
        __syncthreads();
    }
    int incl = buf[tid];
    if (tid == 0) rowptr[0] = 0;
    rowptr[tid + 1] = incl;
    rowfill[tid] = incl - v;
    int lo = 0, hi = SS;
    while (lo < hi) { int mid = (lo + hi) >> 1; if (batch[mid] < tid) lo = mid + 1; else hi = mid; }
    segoff[tid] = lo;
    if (tid == 0) segoff[CC] = SS;
}

// CSR-ordered edge arrays: colS[pos], eawS[pos] (no eidx indirection later)
__global__ void k_prep2(const int* __restrict__ row, const int* __restrict__ col,
                        const float* __restrict__ attr, const float* __restrict__ deg,
                        int* __restrict__ rowfill, int* __restrict__ colS,
                        float* __restrict__ eawS, int E)
{
    int e = blockIdx.x * 256 + threadIdx.x;
    if (e < E) {
        int r = row[e], c = col[e];
        float dr = deg[r], dc = deg[c];
        float ir = dr > 0.f ? 1.f / sqrtf(dr) : 0.f;
        float ic = dc > 0.f ? 1.f / sqrtf(dc) : 0.f;
        int pos = atomicAdd(&rowfill[r], 1);
        colS[pos] = c;
        eawS[pos] = ir * attr[e] * ic;
    }
}

// ---------------------------------------------------------------------------
// k_qk: Qs = (sum_s u[mapper[s]])@Wp2 + L*bp2 ; Qk = relu(relu(Qs@Wpo1+bpo1)@Wpo2+bpo2)
// 4 waves: gather split 4-way; each matvec computed as 4 partial i-slices
// reduced via LDS atomics.
// ---------------------------------------------------------------------------
__global__ __launch_bounds__(256) void k_qk(
    const float* __restrict__ u, const int* __restrict__ mapper,
    const int* __restrict__ segoff,
    const float* __restrict__ Wp2, const float* __restrict__ bp2,
    const float* __restrict__ Wpo1, const float* __restrict__ bpo1,
    const float* __restrict__ Wpo2, const float* __restrict__ bpo2,
    float* __restrict__ Qk)
{
    __shared__ float accs[4][64];
    int c = blockIdx.x;
    int tid = threadIdx.x, j = tid & 63, g = tid >> 6;
    int s0 = segoff[c], s1 = segoff[c + 1];
    float L = (float)(s1 - s0);
    if (tid < 64) {
        accs[0][tid] = 0.f;
        accs[1][tid] = L * bp2[tid];
        accs[2][tid] = bpo1[tid];
        accs[3][tid] = bpo2[tid];
    }
    __syncthreads();
    float us = 0.f;
    for (int s = s0 + g; s < s1; s += 4) us += u[(size_t)mapper[s] * 64 + j];
    atomicAdd(&accs[0][j], us);
    __syncthreads();
    float usv = accs[0][j];
    float p = 0.f;
#pragma unroll
    for (int t = 0; t < 16; ++t) {
        int i = g * 16 + t;
        p = fmaf(rdlane(usv, i), Wp2[i * 64 + j], p);
    }
    atomicAdd(&accs[1][j], p);
    __syncthreads();
    float qs = accs[1][j];
    p = 0.f;
#pragma unroll
    for (int t = 0; t < 16; ++t) {
        int i = g * 16 + t;
        p = fmaf(rdlane(qs, i), Wpo1[i * 64 + j], p);
    }
    atomicAdd(&accs[2][j], p);
    __syncthreads();
    float tv = fmaxf(accs[2][j], 0.f);
    p = 0.f;
#pragma unroll
    for (int t = 0; t < 16; ++t) {
        int i = g * 16 + t;
        p = fmaf(rdlane(tv, i), Wpo2[i * 64 + j], p);
    }
    atomicAdd(&accs[3][j], p);
    __syncthreads();
    if (g == 0) Qk[c * 64 + j] = fmaxf(accs[3][j], 0.f);
}

// ---------------------------------------------------------------------------
// k_msb_edges: block per source cluster r (skipped if no out-edges).
// P1: 2x2 wave split — waves {0,1} build rows 0..31 over even/odd entries,
//     waves {2,3} rows 32..63; 32-reg partials. ks/krs/vs from waves 0,1.
// P2: ds_add_f32 reduce into transposed LDS msbT[j][i] (stride 68).
// P3: edges split across 4 waves; per edge: gather Qk[c] (1-deep prefetch),
//     wj = sum_i Qk[c][i]*Msb[r][i][j] via 16x ds_read_b128 + readlane FMA,
//     plus the rank-1 (Ksk,Vsum) and den terms; atomics into H/den.
// ---------------------------------------------------------------------------
__global__ __launch_bounds__(256) void k_msb_edges(
    const float* __restrict__ KV, const int* __restrict__ mapper,
    const int* __restrict__ segoff, const float* __restrict__ Qk,
    const float* __restrict__ eawS, const int* __restrict__ colS,
    const int* __restrict__ rowptr, const float* __restrict__ ab,
    float* __restrict__ H, float* __restrict__ den)
{
    __shared__ __align__(16) float msbT[64 * TS];
    __shared__ float sums[3 * 64];
    int r = blockIdx.x;
    int e0 = rowptr[r], e1 = rowptr[r + 1];
    if (e0 == e1) return;
    int tid = threadIdx.x, j = tid & 63, g = tid >> 6;
    for (int t = tid; t < 64 * TS; t += 256) msbT[t] = 0.f;
    if (tid < 192) sums[tid] = 0.f;
    __syncthreads();
    int s0 = segoff[r], s1 = segoff[r + 1];
    int rbase = (g >> 1) * 32;
    float msb[32];
#pragma unroll
    for (int i = 0; i < 32; ++i) msb[i] = 0.f;
    float ks = 0.f, krs = 0.f, vs = 0.f;
    int sstart = s0 + (g & 1);
    if (sstart < s1) {
        int m = mapper[sstart];
        float kj = KV[(size_t)m * 128 + j];
        float vj = KV[(size_t)m * 128 + 64 + j];
        for (int s = sstart; s < s1; s += 2) {
            float kjc = kj, vjc = vj;
            int sn = s + 2;
            if (sn < s1) {
                int m2 = mapper[sn];
                kj = KV[(size_t)m2 * 128 + j];
                vj = KV[(size_t)m2 * 128 + 64 + j];
            }
            float kr = fmaxf(kjc, 0.f);
            if (rbase == 0) { ks += kjc; krs += kr; vs += vjc; }
#pragma unroll
            for (int i = 0; i < 32; ++i)
                msb[i] = fmaf(rdlane(kr, rbase + i), vjc, msb[i]);
        }
    }
#pragma unroll
    for (int i = 0; i < 32; ++i) atomicAdd(&msbT[j * TS + rbase + i], msb[i]);
    if (rbase == 0) {
        atomicAdd(&sums[j], ks);
        atomicAdd(&sums[64 + j], krs);
        atomicAdd(&sums[128 + j], vs);
    }
    __syncthreads();
    int L = s1 - s0;
    float Lr = (float)L;
    float Lm = (float)(L > 0 ? L : 1);
    float kskj = fmaxf(sums[j] / Lm, 0.f);
    float krj = sums[64 + j];
    float vsj = sums[128 + j];
    float a0 = ab[0], a1 = ab[1];
    float sa2 = 1.f + expf(a1 - a0);   // 1/softmax0
    float sb2 = 1.f + expf(a0 - a1);   // 1/softmax1

    int idx = e0 + g;
    if (idx >= e1) return;
    int c = colS[idx];
    float w = eawS[idx];
    float qv = Qk[c * 64 + j];
    const float* mrow = &msbT[j * TS];
    for (; idx < e1; ) {
        int cc = c; float wc = w, qc = qv;
        int idx2 = idx + 4;
        if (idx2 < e1) {
            c = colS[idx2];
            w = eawS[idx2];
            qv = Qk[c * 64 + j];
        }
        float wj0 = 0.f, wj1 = 0.f, wj2 = 0.f, wj3 = 0.f;
#pragma unroll
        for (int t = 0; t < 16; ++t) {
            float4 mv = *(const float4*)(mrow + 4 * t);
            wj0 = fmaf(rdlane(qc, 4 * t + 0), mv.x, wj0);
            wj1 = fmaf(rdlane(qc, 4 * t + 1), mv.y, wj1);
            wj2 = fmaf(rdlane(qc, 4 * t + 2), mv.z, wj2);
            wj3 = fmaf(rdlane(qc, 4 * t + 3), mv.w, wj3);
        }
        float wjt = (wj0 + wj1) + (wj2 + wj3);
        float p1 = qc * kskj;
        float p2 = qc * krj;
#pragma unroll
        for (int o = 32; o > 0; o >>= 1) { p1 += __shfl_xor(p1, o); p2 += __shfl_xor(p2, o); }
        atomicAdd(&H[cc * 64 + j], wc * (sb2 * wjt + sa2 * p1 * vsj));
        if (j == 0) atomicAdd(&den[cc], wc * (sa2 * Lr * p1 + sb2 * p2));
        idx = idx2;
    }
}

// ---------------------------------------------------------------------------
__global__ __launch_bounds__(64) void k_final(
    const float* __restrict__ H, const float* __restrict__ den,
    const float* __restrict__ Wc1, const float* __restrict__ bc1,
    const float* __restrict__ Wc2, const float* __restrict__ bc2,
    float* __restrict__ out)
{
    int bg = blockIdx.x;
    int j = threadIdx.x;
    float acc = 0.f;
    for (int p = 0; p < PP; ++p) {
        int c = bg * PP + p;
        acc += H[c * 64 + j] / (den[c] + 1e-6f);
    }
    float g = acc * (1.f / (float)PP);
    int m = j & 31;
    float a1 = bc1[m];
#pragma unroll
    for (int i = 0; i < 64; ++i) a1 = fmaf(rdlane(g, i), Wc1[i * 32 + m], a1);
    float c1 = fmaxf(a1, 0.f);
    int n = (j < NC) ? j : 0;
    float a2 = bc2[n];
#pragma unroll
    for (int i = 0; i < 32; ++i) a2 = fmaf(rdlane(c1, i), Wc2[i * NC + n], a2);
    if (j < NC) out[bg * NC + j] = a2;
}

// ---------------------------------------------------------------------------
extern "C" void kernel_launch(void* const* d_in, const int* in_sizes, int n_in,
                              void* d_out, int out_size, void* d_ws, size_t ws_size,
                              hipStream_t stream)
{
    const float* x      = (const float*)d_in[0];
    const int*   mapper = (const int*)d_in[1];
    const int*   batch  = (const int*)d_in[2];
    const int*   row    = (const int*)d_in[3];
    const int*   col    = (const int*)d_in[4];
    const float* attr   = (const float*)d_in[5];
    const float* W_in1  = (const float*)d_in[6];
    const float* b_in1  = (const float*)d_in[7];
    const float* W_in2  = (const float*)d_in[8];
    const float* b_in2  = (const float*)d_in[9];
    const float* W_pre1 = (const float*)d_in[10];
    const float* b_pre1 = (const float*)d_in[11];
    const float* W_pre2 = (const float*)d_in[12];
    const float* b_pre2 = (const float*)d_in[13];
    const float* W_post1= (const float*)d_in[14];
    const float* b_post1= (const float*)d_in[15];
    const float* W_post2= (const float*)d_in[16];
    const float* b_post2= (const float*)d_in[17];
    const float* W_K    = (const float*)d_in[18];
    const float* b_K    = (const float*)d_in[19];
    const float* W_V    = (const float*)d_in[20];
    const float* b_V    = (const float*)d_in[21];
    const float* alpha_beta = (const float*)d_in[22];
    const float* W_c1   = (const float*)d_in[23];
    const float* b_c1   = (const float*)d_in[24];
    const float* W_c2   = (const float*)d_in[25];
    const float* b_c2   = (const float*)d_in[26];

    float* ws = (float*)d_ws;
    float* u     = ws;                        // N*64
    float* KV    = u     + (size_t)NN * 64;   // N*128 (K | V interleaved rows)
    float* Qk    = KV    + (size_t)NN * 128;  // C*64
    float* eawS  = Qk    + (size_t)CC * 64;   // E (CSR order)
    // --- zeroed region (contiguous) ---
    float* H     = eawS  + (size_t)EE;        // C*64
    float* den   = H     + (size_t)CC * 64;   // C
    float* deg   = den   + (size_t)CC;        // C
    int*  rowcnt = (int*)(deg + (size_t)CC);  // C
    // --- end zeroed region ---
    int*  segoff = rowcnt + CC;               // C+1
    int*  rowptr = segoff + (CC + 1);         // C+1
    int*  rowfill= rowptr + (CC + 1);         // C
    int*  colS   = rowfill + CC;              // E (CSR order)

    size_t zero_bytes = ((size_t)CC * 64 + CC + CC + CC) * sizeof(float);
    hipMemsetAsync(H, 0, zero_bytes, stream);

    k_prep1<<<EE / 256, 256, 0, stream>>>(row, attr, deg, rowcnt, EE);
    k_scan<<<1, 1024, 0, stream>>>(rowcnt, rowptr, rowfill, batch, segoff);
    k_prep2<<<EE / 256, 256, 0, stream>>>(row, col, attr, deg, rowfill, colS, eawS, EE);
    k_node<<<NN / 64, 256, 0, stream>>>(x, W_in1, b_in1, W_in2, b_in2,
                                        W_pre1, b_pre1, W_K, b_K, W_V, b_V, u, KV);
    k_qk<<<CC, 256, 0, stream>>>(u, mapper, segoff, W_pre2, b_pre2,
                                 W_post1, b_post1, W_post2, b_post2, Qk);
    k_msb_edges<<<CC, 256, 0, stream>>>(KV, mapper, segoff, Qk, eawS, colS,
                                        rowptr, alpha_beta, H, den);
    k_final<<<BB, 64, 0, stream>>>(H, den, W_c1, b_c1, W_c2, b_c2, (float*)d_out);
}

// Round 5
// 107.172 us; speedup vs baseline: 1.3443x; 1.3294x over previous
//
#include <hip/hip_runtime.h>
#include <math.h>

constexpr int NN = 32768;   // nodes
constexpr int SS = 32768;   // subgraph-node entries
constexpr int CC = 1024;    // clusters
constexpr int EE = 16384;   // coarsen edges
constexpr int BB = 16;      // graphs
constexpr int PP = 64;      // patches per graph
constexpr int NC = 10;      // classes

__device__ __forceinline__ float rdlane(float v, int l) {
    return __int_as_float(__builtin_amdgcn_readlane(__float_as_int(v), l));
}

// ---------------------------------------------------------------------------
// k_node: fused per-node dense chain, 5 GEMM phases on a 64x64 row tile:
//   t1 = relu(x@W1+b1); h = relu(t1@W2+b2); u = relu(h@Wp1+bp1)  -> u (global)
//   K = h@WK+bK -> KV[:,0:64];  V = h@WV+bV -> KV[:,64:128]
// (Wp2 applied later in k_msb via linearity: Qs = (sum u)@Wp2 + L*bp2.)
// ---------------------------------------------------------------------------
#define TS 68

__device__ __forceinline__ void gemm64(const float* A, const float* W,
                                       const float* __restrict__ bias,
                                       int r0, int c0, float acc[4][4])
{
#pragma unroll
    for (int dc = 0; dc < 4; ++dc) {
        float bv = bias[c0 + dc];
        acc[0][dc] = bv; acc[1][dc] = bv; acc[2][dc] = bv; acc[3][dc] = bv;
    }
#pragma unroll 16
    for (int k = 0; k < 64; ++k) {
        float4 av = *(const float4*)(A + k * TS + r0);
        float4 wv = *(const float4*)(W + k * TS + c0);
        acc[0][0] = fmaf(av.x, wv.x, acc[0][0]); acc[0][1] = fmaf(av.x, wv.y, acc[0][1]);
        acc[0][2] = fmaf(av.x, wv.z, acc[0][2]); acc[0][3] = fmaf(av.x, wv.w, acc[0][3]);
        acc[1][0] = fmaf(av.y, wv.x, acc[1][0]); acc[1][1] = fmaf(av.y, wv.y, acc[1][1]);
        acc[1][2] = fmaf(av.y, wv.z, acc[1][2]); acc[1][3] = fmaf(av.y, wv.w, acc[1][3]);
        acc[2][0] = fmaf(av.z, wv.x, acc[2][0]); acc[2][1] = fmaf(av.z, wv.y, acc[2][1]);
        acc[2][2] = fmaf(av.z, wv.z, acc[2][2]); acc[2][3] = fmaf(av.z, wv.w, acc[2][3]);
        acc[3][0] = fmaf(av.w, wv.x, acc[3][0]); acc[3][1] = fmaf(av.w, wv.y, acc[3][1]);
        acc[3][2] = fmaf(av.w, wv.z, acc[3][2]); acc[3][3] = fmaf(av.w, wv.w, acc[3][3]);
    }
}

__device__ __forceinline__ void stageW(float* dst, const float* __restrict__ src, int tid)
{
#pragma unroll
    for (int t = 0; t < 16; ++t) {
        int idx = tid + t * 256;
        dst[(idx >> 6) * TS + (idx & 63)] = src[idx];
    }
}

__device__ __forceinline__ void outT_relu(float* dst, int r0, int c0, float acc[4][4])
{
#pragma unroll
    for (int dc = 0; dc < 4; ++dc) {
        *(float4*)(dst + (c0 + dc) * TS + r0) =
            make_float4(fmaxf(acc[0][dc], 0.f), fmaxf(acc[1][dc], 0.f),
                        fmaxf(acc[2][dc], 0.f), fmaxf(acc[3][dc], 0.f));
    }
}

__device__ __forceinline__ void outG2(float* __restrict__ dst, size_t rowbase, int ld,
                                      int off, int r0, int c0, float acc[4][4], bool dorelu)
{
#pragma unroll
    for (int dr = 0; dr < 4; ++dr) {
        float4 v = make_float4(acc[dr][0], acc[dr][1], acc[dr][2], acc[dr][3]);
        if (dorelu) {
            v.x = fmaxf(v.x, 0.f); v.y = fmaxf(v.y, 0.f);
            v.z = fmaxf(v.z, 0.f); v.w = fmaxf(v.w, 0.f);
        }
        *(float4*)(dst + (rowbase + r0 + dr) * ld + off + c0) = v;
    }
}

__global__ __launch_bounds__(256) void k_node(
    const float* __restrict__ x,
    const float* __restrict__ W1, const float* __restrict__ b1,
    const float* __restrict__ W2, const float* __restrict__ b2,
    const float* __restrict__ Wp1, const float* __restrict__ bp1,
    const float* __restrict__ WK, const float* __restrict__ bK,
    const float* __restrict__ WV, const float* __restrict__ bV,
    float* __restrict__ u, float* __restrict__ KV)
{
    __shared__ __align__(16) float bufA[64 * TS];
    __shared__ __align__(16) float bufB[64 * TS];
    __shared__ __align__(16) float wlds[64 * TS];
    int tid = threadIdx.x;
    int tx = tid & 15, ty = tid >> 4;
    int r0 = ty * 4, c0 = tx * 4;
    size_t rowbase = (size_t)blockIdx.x * 64;
    const float* xb = x + rowbase * 64;
#pragma unroll
    for (int t = 0; t < 16; ++t) {
        int idx = tid + t * 256;
        bufA[(idx & 63) * TS + (idx >> 6)] = xb[idx];
    }
    stageW(wlds, W1, tid);
    __syncthreads();
    float acc[4][4];
    gemm64(bufA, wlds, b1, r0, c0, acc);
    outT_relu(bufB, r0, c0, acc);
    __syncthreads();
    stageW(wlds, W2, tid);
    __syncthreads();
    gemm64(bufB, wlds, b2, r0, c0, acc);
    outT_relu(bufA, r0, c0, acc);
    __syncthreads();
    stageW(wlds, Wp1, tid);
    __syncthreads();
    gemm64(bufA, wlds, bp1, r0, c0, acc);
    outG2(u, rowbase, 64, 0, r0, c0, acc, true);
    __syncthreads();
    stageW(wlds, WK, tid);
    __syncthreads();
    gemm64(bufA, wlds, bK, r0, c0, acc);
    outG2(KV, rowbase, 128, 0, r0, c0, acc, false);
    __syncthreads();
    stageW(wlds, WV, tid);
    __syncthreads();
    gemm64(bufA, wlds, bV, r0, c0, acc);
    outG2(KV, rowbase, 128, 64, r0, c0, acc, false);
}

// ---------------------------------------------------------------------------
__global__ void k_prep1(const int* __restrict__ row, const float* __restrict__ attr,
                        float* __restrict__ deg, int* __restrict__ rowcnt, int E)
{
    int e = blockIdx.x * 256 + threadIdx.x;
    if (e < E) {
        int r = row[e];
        atomicAdd(&deg[r], attr[e]);
        atomicAdd(&rowcnt[r], 1);
    }
}

__global__ __launch_bounds__(1024) void k_scan(
    const int* __restrict__ rowcnt, int* __restrict__ rowptr, int* __restrict__ rowfill,
    const int* __restrict__ batch, int* __restrict__ segoff)
{
    __shared__ int buf[1024];
    int tid = threadIdx.x;
    int v = rowcnt[tid];
    buf[tid] = v;
    __syncthreads();
    for (int off = 1; off < 1024; off <<= 1) {
        int t = (tid >= off) ? buf[tid - off] : 0;
        __syncthreads();
        buf[tid] += t;
        __syncthreads();
    }
    int incl = buf[tid];
    if (tid == 0) rowptr[0] = 0;
    rowptr[tid + 1] = incl;
    rowfill[tid] = incl - v;
    int lo = 0, hi = SS;
    while (lo < hi) { int mid = (lo + hi) >> 1; if (batch[mid] < tid) lo = mid + 1; else hi = mid; }
    segoff[tid] = lo;
    if (tid == 0) segoff[CC] = SS;
}

__global__ void k_prep2(const int* __restrict__ row, const int* __restrict__ col,
                        const float* __restrict__ attr, const float* __restrict__ deg,
                        int* __restrict__ rowfill, int* __restrict__ colS,
                        float* __restrict__ eawS, int E)
{
    int e = blockIdx.x * 256 + threadIdx.x;
    if (e < E) {
        int r = row[e], c = col[e];
        float dr = deg[r], dc = deg[c];
        float ir = dr > 0.f ? 1.f / sqrtf(dr) : 0.f;
        float ic = dc > 0.f ? 1.f / sqrtf(dc) : 0.f;
        int pos = atomicAdd(&rowfill[r], 1);
        colS[pos] = c;
        eawS[pos] = ir * attr[e] * ic;
    }
}

// ---------------------------------------------------------------------------
// k_msb: block per cluster. Stages K/V entry chunks into LDS, then a GEMM
// encoding (16x16 threads, acc[4][4] named registers, ds_read_b128) builds
// Msb[c] = relu(K)^T @ V. Also computes Ksk/Krsum/Vsum/Lf and the full Q
// path (u-sum -> Wp2 -> post-MLP -> Qk). No per-thread arrays beyond acc.
// ---------------------------------------------------------------------------
#define KSTR 72

__global__ __launch_bounds__(256, 4) void k_msb(
    const float* __restrict__ u, const float* __restrict__ KV,
    const int* __restrict__ mapper, const int* __restrict__ segoff,
    const float* __restrict__ Wp2, const float* __restrict__ bp2,
    const float* __restrict__ Wpo1, const float* __restrict__ bpo1,
    const float* __restrict__ Wpo2, const float* __restrict__ bpo2,
    float* __restrict__ Msb, float* __restrict__ Qk, float* __restrict__ Ksk,
    float* __restrict__ Krsum, float* __restrict__ Vsum, float* __restrict__ Lf)
{
    __shared__ __align__(16) float Kr[32 * KSTR];
    __shared__ __align__(16) float Vb[32 * KSTR];
    __shared__ int map_lds[32];
    __shared__ float sums[256];          // [qs | ks | krs | vs] x 64
    __shared__ float redu0[64], redu1[64], redu2[64];
    int c = blockIdx.x;
    int tid = threadIdx.x, j = tid & 63, g = tid >> 6;
    int tx = tid & 15, ty = tid >> 4;
    int r0 = ty * 4, c0 = tx * 4;
    int s0 = segoff[c], s1 = segoff[c + 1];
    sums[tid] = 0.f;
    float acc[4][4];
#pragma unroll
    for (int a = 0; a < 4; ++a)
#pragma unroll
        for (int b = 0; b < 4; ++b) acc[a][b] = 0.f;
    float qs = 0.f, ks = 0.f, krs = 0.f, vs = 0.f;
    __syncthreads();
    for (int sb = s0; sb < s1; sb += 32) {
        int clen = min(32, s1 - sb);
        __syncthreads();   // protect previous chunk's LDS before overwrite
        if (tid < clen) map_lds[tid] = mapper[sb + tid];
        __syncthreads();
        for (int p = tid; p < clen * 32; p += 256) {
            int e = p >> 5, q = p & 31;
            int m = map_lds[e];
            float4 v = *(const float4*)(KV + (size_t)m * 128 + q * 4);
            float* dst = (q < 16) ? &Kr[e * KSTR + q * 4] : &Vb[e * KSTR + (q - 16) * 4];
            *(float4*)dst = v;
        }
        __syncthreads();
#pragma unroll 4
        for (int s = 0; s < clen; ++s) {
            float4 a4 = *(const float4*)(&Kr[s * KSTR + r0]);
            float4 b4 = *(const float4*)(&Vb[s * KSTR + c0]);
            float ar0 = fmaxf(a4.x, 0.f), ar1 = fmaxf(a4.y, 0.f);
            float ar2 = fmaxf(a4.z, 0.f), ar3 = fmaxf(a4.w, 0.f);
            acc[0][0] = fmaf(ar0, b4.x, acc[0][0]); acc[0][1] = fmaf(ar0, b4.y, acc[0][1]);
            acc[0][2] = fmaf(ar0, b4.z, acc[0][2]); acc[0][3] = fmaf(ar0, b4.w, acc[0][3]);
            acc[1][0] = fmaf(ar1, b4.x, acc[1][0]); acc[1][1] = fmaf(ar1, b4.y, acc[1][1]);
            acc[1][2] = fmaf(ar1, b4.z, acc[1][2]); acc[1][3] = fmaf(ar1, b4.w, acc[1][3]);
            acc[2][0] = fmaf(ar2, b4.x, acc[2][0]); acc[2][1] = fmaf(ar2, b4.y, acc[2][1]);
            acc[2][2] = fmaf(ar2, b4.z, acc[2][2]); acc[2][3] = fmaf(ar2, b4.w, acc[2][3]);
            acc[3][0] = fmaf(ar3, b4.x, acc[3][0]); acc[3][1] = fmaf(ar3, b4.y, acc[3][1]);
            acc[3][2] = fmaf(ar3, b4.z, acc[3][2]); acc[3][3] = fmaf(ar3, b4.w, acc[3][3]);
        }
        for (int s = g; s < clen; s += 4) {
            float kv = Kr[s * KSTR + j];
            ks += kv;
            krs += fmaxf(kv, 0.f);
            vs += Vb[s * KSTR + j];
            qs += u[(size_t)map_lds[s] * 64 + j];
        }
    }
    atomicAdd(&sums[j], qs);
    atomicAdd(&sums[64 + j], ks);
    atomicAdd(&sums[128 + j], krs);
    atomicAdd(&sums[192 + j], vs);
    // write Msb while the reductions land
    size_t mb = (size_t)c * 4096;
#pragma unroll
    for (int a = 0; a < 4; ++a)
        *(float4*)(Msb + mb + (size_t)(r0 + a) * 64 + c0) =
            make_float4(acc[a][0], acc[a][1], acc[a][2], acc[a][3]);
    int L = s1 - s0;
    if (tid < 64) {
        redu0[tid] = (float)L * bp2[tid];
        redu1[tid] = bpo1[tid];
        redu2[tid] = bpo2[tid];
    }
    __syncthreads();
    float qsv = sums[j];
    float Lm = (float)(L > 0 ? L : 1);
    if (g == 0) {
        Ksk[c * 64 + j] = fmaxf(sums[64 + j] / Lm, 0.f);
        Krsum[c * 64 + j] = sums[128 + j];
        Vsum[c * 64 + j] = sums[192 + j];
        if (j == 0) Lf[c] = (float)L;
    }
    float p = 0.f;
#pragma unroll
    for (int t = 0; t < 16; ++t) {
        int i = g * 16 + t;
        p = fmaf(rdlane(qsv, i), Wp2[i * 64 + j], p);
    }
    atomicAdd(&redu0[j], p);
    __syncthreads();
    float q2 = redu0[j];
    p = 0.f;
#pragma unroll
    for (int t = 0; t < 16; ++t) {
        int i = g * 16 + t;
        p = fmaf(rdlane(q2, i), Wpo1[i * 64 + j], p);
    }
    atomicAdd(&redu1[j], p);
    __syncthreads();
    float tt = fmaxf(redu1[j], 0.f);
    p = 0.f;
#pragma unroll
    for (int t = 0; t < 16; ++t) {
        int i = g * 16 + t;
        p = fmaf(rdlane(tt, i), Wpo2[i * 64 + j], p);
    }
    atomicAdd(&redu2[j], p);
    __syncthreads();
    if (tid < 64) Qk[c * 64 + tid] = fmaxf(redu2[tid], 0.f);
}

// ---------------------------------------------------------------------------
// k_edges: block per source r. Stage Msb[r] (16KB) into LDS once (stride 68;
// column reads msb[i*68+j] are conflict-free). 4 waves, each every 4th edge.
// Per edge: 64 ds_read_b32 + 64 readlane-FMA (4 named accumulators), shfl
// reduces for the rank-1/den terms, atomics into H/den. No register arrays.
// ---------------------------------------------------------------------------
#define MSTR 68

__global__ __launch_bounds__(256, 4) void k_edges(
    const float* __restrict__ Msb, const float* __restrict__ Qk,
    const float* __restrict__ Ksk, const float* __restrict__ Krsum,
    const float* __restrict__ Vsum, const float* __restrict__ Lf,
    const float* __restrict__ eawS, const int* __restrict__ colS,
    const int* __restrict__ rowptr, const float* __restrict__ ab,
    float* __restrict__ H, float* __restrict__ den)
{
    __shared__ __align__(16) float msb[64 * MSTR];
    int r = blockIdx.x;
    int e0 = rowptr[r], e1 = rowptr[r + 1];
    if (e0 == e1) return;
    int tid = threadIdx.x, j = tid & 63, g = tid >> 6;
    size_t mb = (size_t)r * 4096;
    for (int p = tid; p < 1024; p += 256) {
        float4 v = *(const float4*)(Msb + mb + (size_t)p * 4);
        int i = p >> 4, j0 = (p & 15) * 4;
        *(float4*)(&msb[i * MSTR + j0]) = v;
    }
    float kskj = Ksk[r * 64 + j];
    float krj  = Krsum[r * 64 + j];
    float vsj  = Vsum[r * 64 + j];
    float Lr   = Lf[r];
    float a0 = ab[0], a1 = ab[1];
    float sa2 = 1.f + expf(a1 - a0);   // 1/softmax0
    float sb2 = 1.f + expf(a0 - a1);   // 1/softmax1
    __syncthreads();
    int idx = e0 + g;
    if (idx >= e1) return;
    int c = colS[idx];
    float w = eawS[idx];
    float qv = Qk[c * 64 + j];
    while (true) {
        int cc = c; float wc = w, qc = qv;
        int nidx = idx + 4;
        if (nidx < e1) {
            c = colS[nidx];
            w = eawS[nidx];
            qv = Qk[c * 64 + j];
        }
        float wj0 = 0.f, wj1 = 0.f, wj2 = 0.f, wj3 = 0.f;
#pragma unroll
        for (int t = 0; t < 16; ++t) {
            wj0 = fmaf(rdlane(qc, 4 * t + 0), msb[(4 * t + 0) * MSTR + j], wj0);
            wj1 = fmaf(rdlane(qc, 4 * t + 1), msb[(4 * t + 1) * MSTR + j], wj1);
            wj2 = fmaf(rdlane(qc, 4 * t + 2), msb[(4 * t + 2) * MSTR + j], wj2);
            wj3 = fmaf(rdlane(qc, 4 * t + 3), msb[(4 * t + 3) * MSTR + j], wj3);
        }
        float wjt = (wj0 + wj1) + (wj2 + wj3);
        float p1 = qc * kskj;
        float p2 = qc * krj;
#pragma unroll
        for (int o = 32; o > 0; o >>= 1) { p1 += __shfl_xor(p1, o); p2 += __shfl_xor(p2, o); }
        atomicAdd(&H[cc * 64 + j], wc * (sb2 * wjt + sa2 * p1 * vsj));
        if (j == 0) atomicAdd(&den[cc], wc * (sa2 * Lr * p1 + sb2 * p2));
        idx = nidx;
        if (idx >= e1) break;
    }
}

// ---------------------------------------------------------------------------
__global__ __launch_bounds__(64) void k_final(
    const float* __restrict__ H, const float* __restrict__ den,
    const float* __restrict__ Wc1, const float* __restrict__ bc1,
    const float* __restrict__ Wc2, const float* __restrict__ bc2,
    float* __restrict__ out)
{
    int bg = blockIdx.x;
    int j = threadIdx.x;
    float acc = 0.f;
    for (int p = 0; p < PP; ++p) {
        int c = bg * PP + p;
        acc += H[c * 64 + j] / (den[c] + 1e-6f);
    }
    float g = acc * (1.f / (float)PP);
    int m = j & 31;
    float a1 = bc1[m];
#pragma unroll
    for (int i = 0; i < 64; ++i) a1 = fmaf(rdlane(g, i), Wc1[i * 32 + m], a1);
    float c1 = fmaxf(a1, 0.f);
    int n = (j < NC) ? j : 0;
    float a2 = bc2[n];
#pragma unroll
    for (int i = 0; i < 32; ++i) a2 = fmaf(rdlane(c1, i), Wc2[i * NC + n], a2);
    if (j < NC) out[bg * NC + j] = a2;
}

// ---------------------------------------------------------------------------
extern "C" void kernel_launch(void* const* d_in, const int* in_sizes, int n_in,
                              void* d_out, int out_size, void* d_ws, size_t ws_size,
                              hipStream_t stream)
{
    const float* x      = (const float*)d_in[0];
    const int*   mapper = (const int*)d_in[1];
    const int*   batch  = (const int*)d_in[2];
    const int*   row    = (const int*)d_in[3];
    const int*   col    = (const int*)d_in[4];
    const float* attr   = (const float*)d_in[5];
    const float* W_in1  = (const float*)d_in[6];
    const float* b_in1  = (const float*)d_in[7];
    const float* W_in2  = (const float*)d_in[8];
    const float* b_in2  = (const float*)d_in[9];
    const float* W_pre1 = (const float*)d_in[10];
    const float* b_pre1 = (const float*)d_in[11];
    const float* W_pre2 = (const float*)d_in[12];
    const float* b_pre2 = (const float*)d_in[13];
    const float* W_post1= (const float*)d_in[14];
    const float* b_post1= (const float*)d_in[15];
    const float* W_post2= (const float*)d_in[16];
    const float* b_post2= (const float*)d_in[17];
    const float* W_K    = (const float*)d_in[18];
    const float* b_K    = (const float*)d_in[19];
    const float* W_V    = (const float*)d_in[20];
    const float* b_V    = (const float*)d_in[21];
    const float* alpha_beta = (const float*)d_in[22];
    const float* W_c1   = (const float*)d_in[23];
    const float* b_c1   = (const float*)d_in[24];
    const float* W_c2   = (const float*)d_in[25];
    const float* b_c2   = (const float*)d_in[26];

    float* ws = (float*)d_ws;
    float* u     = ws;                        // N*64
    float* KV    = u     + (size_t)NN * 64;   // N*128
    float* Qk    = KV    + (size_t)NN * 128;  // C*64
    float* eawS  = Qk    + (size_t)CC * 64;   // E (CSR order)
    float* Msb   = eawS  + (size_t)EE;        // C*4096
    float* Ksk   = Msb   + (size_t)CC * 4096; // C*64
    float* Krsum = Ksk   + (size_t)CC * 64;   // C*64
    float* Vsum  = Krsum + (size_t)CC * 64;   // C*64
    float* Lf    = Vsum  + (size_t)CC * 64;   // C
    // --- zeroed region (contiguous) ---
    float* H     = Lf    + (size_t)CC;        // C*64
    float* den   = H     + (size_t)CC * 64;   // C
    float* deg   = den   + (size_t)CC;        // C
    int*  rowcnt = (int*)(deg + (size_t)CC);  // C
    // --- end zeroed region ---
    int*  segoff = rowcnt + CC;               // C+1
    int*  rowptr = segoff + (CC + 1);         // C+1
    int*  rowfill= rowptr + (CC + 1);         // C
    int*  colS   = rowfill + CC;              // E (CSR order)

    size_t zero_bytes = ((size_t)CC * 64 + CC + CC + CC) * sizeof(float);
    hipMemsetAsync(H, 0, zero_bytes, stream);

    k_prep1<<<EE / 256, 256, 0, stream>>>(row, attr, deg, rowcnt, EE);
    k_scan<<<1, 1024, 0, stream>>>(rowcnt, rowptr, rowfill, batch, segoff);
    k_prep2<<<EE / 256, 256, 0, stream>>>(row, col, attr, deg, rowfill, colS, eawS, EE);
    k_node<<<NN / 64, 256, 0, stream>>>(x, W_in1, b_in1, W_in2, b_in2,
                                        W_pre1, b_pre1, W_K, b_K, W_V, b_V, u, KV);
    k_msb<<<CC, 256, 0, stream>>>(u, KV, mapper, segoff,
                                  W_pre2, b_pre2, W_post1, b_post1,
                                  W_post2, b_post2,
                                  Msb, Qk, Ksk, Krsum, Vsum, Lf);
    k_edges<<<CC, 256, 0, stream>>>(Msb, Qk, Ksk, Krsum, Vsum, Lf, eawS, colS,
                                    rowptr, alpha_beta, H, den);
    k_final<<<BB, 64, 0, stream>>>(H, den, W_c1, b_c1, W_c2, b_c2, (float*)d_out);
}

// Round 6
// 105.270 us; speedup vs baseline: 1.3686x; 1.0181x over previous
//
#include <hip/hip_runtime.h>
#include <math.h>

constexpr int NN = 32768;   // nodes
constexpr int SS = 32768;   // subgraph-node entries
constexpr int CC = 1024;    // clusters
constexpr int EE = 16384;   // coarsen edges
constexpr int BB = 16;      // graphs
constexpr int PP = 64;      // patches per graph
constexpr int NC = 10;      // classes

__device__ __forceinline__ float rdlane(float v, int l) {
    return __int_as_float(__builtin_amdgcn_readlane(__float_as_int(v), l));
}

// ---------------------------------------------------------------------------
// k_zero: zero the accumulator region (H, den, deg, rowcnt) with a proper
// grid. 67 blocks x 256 threads x float4 = 68608 floats exactly.
// (The rocclr fillBuffer kernel took ~40us for this; we do it in ~2us.)
// ---------------------------------------------------------------------------
__global__ __launch_bounds__(256) void k_zero(float* __restrict__ zbase)
{
    int i = blockIdx.x * 256 + threadIdx.x;
    *(float4*)(zbase + (size_t)i * 4) = make_float4(0.f, 0.f, 0.f, 0.f);
}

// ---------------------------------------------------------------------------
// k_node: fused per-node dense chain on a 64x64 row tile:
//   t1 = relu(x@W1+b1); h = relu(t1@W2+b2); u = relu(h@Wp1+bp1) -> u
//   K = h@WK+bK, V = h@WV+bV (fused dual-accumulator phase) -> KV
// ---------------------------------------------------------------------------
#define TS 68

__device__ __forceinline__ void gemm64(const float* A, const float* W,
                                       const float* __restrict__ bias,
                                       int r0, int c0, float acc[4][4])
{
#pragma unroll
    for (int dc = 0; dc < 4; ++dc) {
        float bv = bias[c0 + dc];
        acc[0][dc] = bv; acc[1][dc] = bv; acc[2][dc] = bv; acc[3][dc] = bv;
    }
#pragma unroll 16
    for (int k = 0; k < 64; ++k) {
        float4 av = *(const float4*)(A + k * TS + r0);
        float4 wv = *(const float4*)(W + k * TS + c0);
        acc[0][0] = fmaf(av.x, wv.x, acc[0][0]); acc[0][1] = fmaf(av.x, wv.y, acc[0][1]);
        acc[0][2] = fmaf(av.x, wv.z, acc[0][2]); acc[0][3] = fmaf(av.x, wv.w, acc[0][3]);
        acc[1][0] = fmaf(av.y, wv.x, acc[1][0]); acc[1][1] = fmaf(av.y, wv.y, acc[1][1]);
        acc[1][2] = fmaf(av.y, wv.z, acc[1][2]); acc[1][3] = fmaf(av.y, wv.w, acc[1][3]);
        acc[2][0] = fmaf(av.z, wv.x, acc[2][0]); acc[2][1] = fmaf(av.z, wv.y, acc[2][1]);
        acc[2][2] = fmaf(av.z, wv.z, acc[2][2]); acc[2][3] = fmaf(av.z, wv.w, acc[2][3]);
        acc[3][0] = fmaf(av.w, wv.x, acc[3][0]); acc[3][1] = fmaf(av.w, wv.y, acc[3][1]);
        acc[3][2] = fmaf(av.w, wv.z, acc[3][2]); acc[3][3] = fmaf(av.w, wv.w, acc[3][3]);
    }
}

__device__ __forceinline__ void gemm64x2(const float* A, const float* W1_, const float* W2_,
                                         const float* __restrict__ bias1,
                                         const float* __restrict__ bias2,
                                         int r0, int c0, float acc1[4][4], float acc2[4][4])
{
#pragma unroll
    for (int dc = 0; dc < 4; ++dc) {
        float bv1 = bias1[c0 + dc], bv2 = bias2[c0 + dc];
#pragma unroll
        for (int dr = 0; dr < 4; ++dr) { acc1[dr][dc] = bv1; acc2[dr][dc] = bv2; }
    }
#pragma unroll 8
    for (int k = 0; k < 64; ++k) {
        float4 av = *(const float4*)(A + k * TS + r0);
        float4 w1 = *(const float4*)(W1_ + k * TS + c0);
        float4 w2 = *(const float4*)(W2_ + k * TS + c0);
        float ar[4] = {av.x, av.y, av.z, av.w};
        float u1[4] = {w1.x, w1.y, w1.z, w1.w};
        float u2[4] = {w2.x, w2.y, w2.z, w2.w};
#pragma unroll
        for (int dr = 0; dr < 4; ++dr)
#pragma unroll
            for (int dc = 0; dc < 4; ++dc) {
                acc1[dr][dc] = fmaf(ar[dr], u1[dc], acc1[dr][dc]);
                acc2[dr][dc] = fmaf(ar[dr], u2[dc], acc2[dr][dc]);
            }
    }
}

__device__ __forceinline__ void stageW(float* dst, const float* __restrict__ src, int tid)
{
#pragma unroll
    for (int t = 0; t < 16; ++t) {
        int idx = tid + t * 256;
        dst[(idx >> 6) * TS + (idx & 63)] = src[idx];
    }
}

__device__ __forceinline__ void outT_relu(float* dst, int r0, int c0, float acc[4][4])
{
#pragma unroll
    for (int dc = 0; dc < 4; ++dc) {
        *(float4*)(dst + (c0 + dc) * TS + r0) =
            make_float4(fmaxf(acc[0][dc], 0.f), fmaxf(acc[1][dc], 0.f),
                        fmaxf(acc[2][dc], 0.f), fmaxf(acc[3][dc], 0.f));
    }
}

__device__ __forceinline__ void outG2(float* __restrict__ dst, size_t rowbase, int ld,
                                      int off, int r0, int c0, float acc[4][4], bool dorelu)
{
#pragma unroll
    for (int dr = 0; dr < 4; ++dr) {
        float4 v = make_float4(acc[dr][0], acc[dr][1], acc[dr][2], acc[dr][3]);
        if (dorelu) {
            v.x = fmaxf(v.x, 0.f); v.y = fmaxf(v.y, 0.f);
            v.z = fmaxf(v.z, 0.f); v.w = fmaxf(v.w, 0.f);
        }
        *(float4*)(dst + (rowbase + r0 + dr) * ld + off + c0) = v;
    }
}

__global__ __launch_bounds__(256) void k_node(
    const float* __restrict__ x,
    const float* __restrict__ W1, const float* __restrict__ b1,
    const float* __restrict__ W2, const float* __restrict__ b2,
    const float* __restrict__ Wp1, const float* __restrict__ bp1,
    const float* __restrict__ WK, const float* __restrict__ bK,
    const float* __restrict__ WV, const float* __restrict__ bV,
    float* __restrict__ u, float* __restrict__ KV)
{
    __shared__ __align__(16) float bufA[64 * TS];
    __shared__ __align__(16) float bufB[64 * TS];
    __shared__ __align__(16) float wlds[64 * TS];
    int tid = threadIdx.x;
    int tx = tid & 15, ty = tid >> 4;
    int r0 = ty * 4, c0 = tx * 4;
    size_t rowbase = (size_t)blockIdx.x * 64;
    const float* xb = x + rowbase * 64;
#pragma unroll
    for (int t = 0; t < 16; ++t) {
        int idx = tid + t * 256;
        bufA[(idx & 63) * TS + (idx >> 6)] = xb[idx];
    }
    stageW(wlds, W1, tid);
    __syncthreads();
    float acc[4][4];
    // P0: t1 = relu(x@W1+b1) -> bufB
    gemm64(bufA, wlds, b1, r0, c0, acc);
    outT_relu(bufB, r0, c0, acc);
    __syncthreads();
    stageW(wlds, W2, tid);
    __syncthreads();
    // P1: h = relu(t1@W2+b2) -> bufA
    gemm64(bufB, wlds, b2, r0, c0, acc);
    outT_relu(bufA, r0, c0, acc);
    __syncthreads();
    stageW(wlds, Wp1, tid);
    __syncthreads();
    // P2: u = relu(h@Wp1+bp1) -> global
    gemm64(bufA, wlds, bp1, r0, c0, acc);
    outG2(u, rowbase, 64, 0, r0, c0, acc, true);
    __syncthreads();
    stageW(wlds, WK, tid);
    stageW(bufB, WV, tid);   // bufB (t1) is dead; reuse as WV buffer
    __syncthreads();
    // P3: K = h@WK+bK, V = h@WV+bV (dual accumulate, single A pass)
    float accV[4][4];
    gemm64x2(bufA, wlds, bufB, bK, bV, r0, c0, acc, accV);
    outG2(KV, rowbase, 128, 0, r0, c0, acc, false);
    outG2(KV, rowbase, 128, 64, r0, c0, accV, false);
}

// ---------------------------------------------------------------------------
__global__ void k_prep1(const int* __restrict__ row, const float* __restrict__ attr,
                        float* __restrict__ deg, int* __restrict__ rowcnt, int E)
{
    int e = blockIdx.x * 256 + threadIdx.x;
    if (e < E) {
        int r = row[e];
        atomicAdd(&deg[r], attr[e]);
        atomicAdd(&rowcnt[r], 1);
    }
}

__global__ __launch_bounds__(1024) void k_scan(
    const int* __restrict__ rowcnt, int* __restrict__ rowptr, int* __restrict__ rowfill,
    const int* __restrict__ batch, int* __restrict__ segoff)
{
    __shared__ int buf[1024];
    int tid = threadIdx.x;
    int v = rowcnt[tid];
    buf[tid] = v;
    __syncthreads();
    for (int off = 1; off < 1024; off <<= 1) {
        int t = (tid >= off) ? buf[tid - off] : 0;
        __syncthreads();
        buf[tid] += t;
        __syncthreads();
    }
    int incl = buf[tid];
    if (tid == 0) rowptr[0] = 0;
    rowptr[tid + 1] = incl;
    rowfill[tid] = incl - v;
    int lo = 0, hi = SS;
    while (lo < hi) { int mid = (lo + hi) >> 1; if (batch[mid] < tid) lo = mid + 1; else hi = mid; }
    segoff[tid] = lo;
    if (tid == 0) segoff[CC] = SS;
}

__global__ void k_prep2(const int* __restrict__ row, const int* __restrict__ col,
                        const float* __restrict__ attr, const float* __restrict__ deg,
                        int* __restrict__ rowfill, int* __restrict__ colS,
                        float* __restrict__ eawS, int E)
{
    int e = blockIdx.x * 256 + threadIdx.x;
    if (e < E) {
        int r = row[e], c = col[e];
        float dr = deg[r], dc = deg[c];
        float ir = dr > 0.f ? 1.f / sqrtf(dr) : 0.f;
        float ic = dc > 0.f ? 1.f / sqrtf(dc) : 0.f;
        int pos = atomicAdd(&rowfill[r], 1);
        colS[pos] = c;
        eawS[pos] = ir * attr[e] * ic;
    }
}

// ---------------------------------------------------------------------------
// k_msb: block per cluster. K/V chunks staged in LDS; GEMM encoding builds
// Msb[c] = relu(K)^T @ V; also Ksk/Krsum/Vsum/Lf and the full Q path -> Qk.
// ---------------------------------------------------------------------------
#define KSTR 72

__global__ __launch_bounds__(256, 4) void k_msb(
    const float* __restrict__ u, const float* __restrict__ KV,
    const int* __restrict__ mapper, const int* __restrict__ segoff,
    const float* __restrict__ Wp2, const float* __restrict__ bp2,
    const float* __restrict__ Wpo1, const float* __restrict__ bpo1,
    const float* __restrict__ Wpo2, const float* __restrict__ bpo2,
    float* __restrict__ Msb, float* __restrict__ Qk, float* __restrict__ Ksk,
    float* __restrict__ Krsum, float* __restrict__ Vsum, float* __restrict__ Lf)
{
    __shared__ __align__(16) float Kr[32 * KSTR];
    __shared__ __align__(16) float Vb[32 * KSTR];
    __shared__ int map_lds[32];
    __shared__ float sums[256];
    __shared__ float redu0[64], redu1[64], redu2[64];
    int c = blockIdx.x;
    int tid = threadIdx.x, j = tid & 63, g = tid >> 6;
    int tx = tid & 15, ty = tid >> 4;
    int r0 = ty * 4, c0 = tx * 4;
    int s0 = segoff[c], s1 = segoff[c + 1];
    sums[tid] = 0.f;
    float acc[4][4];
#pragma unroll
    for (int a = 0; a < 4; ++a)
#pragma unroll
        for (int b = 0; b < 4; ++b) acc[a][b] = 0.f;
    float qs = 0.f, ks = 0.f, krs = 0.f, vs = 0.f;
    __syncthreads();
    for (int sb = s0; sb < s1; sb += 32) {
        int clen = min(32, s1 - sb);
        __syncthreads();
        if (tid < clen) map_lds[tid] = mapper[sb + tid];
        __syncthreads();
        for (int p = tid; p < clen * 32; p += 256) {
            int e = p >> 5, q = p & 31;
            int m = map_lds[e];
            float4 v = *(const float4*)(KV + (size_t)m * 128 + q * 4);
            float* dst = (q < 16) ? &Kr[e * KSTR + q * 4] : &Vb[e * KSTR + (q - 16) * 4];
            *(float4*)dst = v;
        }
        __syncthreads();
#pragma unroll 4
        for (int s = 0; s < clen; ++s) {
            float4 a4 = *(const float4*)(&Kr[s * KSTR + r0]);
            float4 b4 = *(const float4*)(&Vb[s * KSTR + c0]);
            float ar0 = fmaxf(a4.x, 0.f), ar1 = fmaxf(a4.y, 0.f);
            float ar2 = fmaxf(a4.z, 0.f), ar3 = fmaxf(a4.w, 0.f);
            acc[0][0] = fmaf(ar0, b4.x, acc[0][0]); acc[0][1] = fmaf(ar0, b4.y, acc[0][1]);
            acc[0][2] = fmaf(ar0, b4.z, acc[0][2]); acc[0][3] = fmaf(ar0, b4.w, acc[0][3]);
            acc[1][0] = fmaf(ar1, b4.x, acc[1][0]); acc[1][1] = fmaf(ar1, b4.y, acc[1][1]);
            acc[1][2] = fmaf(ar1, b4.z, acc[1][2]); acc[1][3] = fmaf(ar1, b4.w, acc[1][3]);
            acc[2][0] = fmaf(ar2, b4.x, acc[2][0]); acc[2][1] = fmaf(ar2, b4.y, acc[2][1]);
            acc[2][2] = fmaf(ar2, b4.z, acc[2][2]); acc[2][3] = fmaf(ar2, b4.w, acc[2][3]);
            acc[3][0] = fmaf(ar3, b4.x, acc[3][0]); acc[3][1] = fmaf(ar3, b4.y, acc[3][1]);
            acc[3][2] = fmaf(ar3, b4.z, acc[3][2]); acc[3][3] = fmaf(ar3, b4.w, acc[3][3]);
        }
        for (int s = g; s < clen; s += 4) {
            float kv = Kr[s * KSTR + j];
            ks += kv;
            krs += fmaxf(kv, 0.f);
            vs += Vb[s * KSTR + j];
            qs += u[(size_t)map_lds[s] * 64 + j];
        }
    }
    atomicAdd(&sums[j], qs);
    atomicAdd(&sums[64 + j], ks);
    atomicAdd(&sums[128 + j], krs);
    atomicAdd(&sums[192 + j], vs);
    size_t mb = (size_t)c * 4096;
#pragma unroll
    for (int a = 0; a < 4; ++a)
        *(float4*)(Msb + mb + (size_t)(r0 + a) * 64 + c0) =
            make_float4(acc[a][0], acc[a][1], acc[a][2], acc[a][3]);
    int L = s1 - s0;
    if (tid < 64) {
        redu0[tid] = (float)L * bp2[tid];
        redu1[tid] = bpo1[tid];
        redu2[tid] = bpo2[tid];
    }
    __syncthreads();
    float qsv = sums[j];
    float Lm = (float)(L > 0 ? L : 1);
    if (g == 0) {
        Ksk[c * 64 + j] = fmaxf(sums[64 + j] / Lm, 0.f);
        Krsum[c * 64 + j] = sums[128 + j];
        Vsum[c * 64 + j] = sums[192 + j];
        if (j == 0) Lf[c] = (float)L;
    }
    float p = 0.f;
#pragma unroll
    for (int t = 0; t < 16; ++t) {
        int i = g * 16 + t;
        p = fmaf(rdlane(qsv, i), Wp2[i * 64 + j], p);
    }
    atomicAdd(&redu0[j], p);
    __syncthreads();
    float q2 = redu0[j];
    p = 0.f;
#pragma unroll
    for (int t = 0; t < 16; ++t) {
        int i = g * 16 + t;
        p = fmaf(rdlane(q2, i), Wpo1[i * 64 + j], p);
    }
    atomicAdd(&redu1[j], p);
    __syncthreads();
    float tt = fmaxf(redu1[j], 0.f);
    p = 0.f;
#pragma unroll
    for (int t = 0; t < 16; ++t) {
        int i = g * 16 + t;
        p = fmaf(rdlane(tt, i), Wpo2[i * 64 + j], p);
    }
    atomicAdd(&redu2[j], p);
    __syncthreads();
    if (tid < 64) Qk[c * 64 + tid] = fmaxf(redu2[tid], 0.f);
}

// ---------------------------------------------------------------------------
// k_edges: block per source r; Msb[r] staged once into LDS (stride 68);
// 4 waves edge-parallel; no per-thread arrays.
// ---------------------------------------------------------------------------
#define MSTR 68

__global__ __launch_bounds__(256, 4) void k_edges(
    const float* __restrict__ Msb, const float* __restrict__ Qk,
    const float* __restrict__ Ksk, const float* __restrict__ Krsum,
    const float* __restrict__ Vsum, const float* __restrict__ Lf,
    const float* __restrict__ eawS, const int* __restrict__ colS,
    const int* __restrict__ rowptr, const float* __restrict__ ab,
    float* __restrict__ H, float* __restrict__ den)
{
    __shared__ __align__(16) float msb[64 * MSTR];
    int r = blockIdx.x;
    int e0 = rowptr[r], e1 = rowptr[r + 1];
    if (e0 == e1) return;
    int tid = threadIdx.x, j = tid & 63, g = tid >> 6;
    size_t mb = (size_t)r * 4096;
    for (int p = tid; p < 1024; p += 256) {
        float4 v = *(const float4*)(Msb + mb + (size_t)p * 4);
        int i = p >> 4, j0 = (p & 15) * 4;
        *(float4*)(&msb[i * MSTR + j0]) = v;
    }
    float kskj = Ksk[r * 64 + j];
    float krj  = Krsum[r * 64 + j];
    float vsj  = Vsum[r * 64 + j];
    float Lr   = Lf[r];
    float a0 = ab[0], a1 = ab[1];
    float sa2 = 1.f + expf(a1 - a0);
    float sb2 = 1.f + expf(a0 - a1);
    __syncthreads();
    int idx = e0 + g;
    if (idx >= e1) return;
    int c = colS[idx];
    float w = eawS[idx];
    float qv = Qk[c * 64 + j];
    while (true) {
        int cc = c; float wc = w, qc = qv;
        int nidx = idx + 4;
        if (nidx < e1) {
            c = colS[nidx];
            w = eawS[nidx];
            qv = Qk[c * 64 + j];
        }
        float wj0 = 0.f, wj1 = 0.f, wj2 = 0.f, wj3 = 0.f;
#pragma unroll
        for (int t = 0; t < 16; ++t) {
            wj0 = fmaf(rdlane(qc, 4 * t + 0), msb[(4 * t + 0) * MSTR + j], wj0);
            wj1 = fmaf(rdlane(qc, 4 * t + 1), msb[(4 * t + 1) * MSTR + j], wj1);
            wj2 = fmaf(rdlane(qc, 4 * t + 2), msb[(4 * t + 2) * MSTR + j], wj2);
            wj3 = fmaf(rdlane(qc, 4 * t + 3), msb[(4 * t + 3) * MSTR + j], wj3);
        }
        float wjt = (wj0 + wj1) + (wj2 + wj3);
        float p1 = qc * kskj;
        float p2 = qc * krj;
#pragma unroll
        for (int o = 32; o > 0; o >>= 1) { p1 += __shfl_xor(p1, o); p2 += __shfl_xor(p2, o); }
        atomicAdd(&H[cc * 64 + j], wc * (sb2 * wjt + sa2 * p1 * vsj));
        if (j == 0) atomicAdd(&den[cc], wc * (sa2 * Lr * p1 + sb2 * p2));
        idx = nidx;
        if (idx >= e1) break;
    }
}

// ---------------------------------------------------------------------------
__global__ __launch_bounds__(64) void k_final(
    const float* __restrict__ H, const float* __restrict__ den,
    const float* __restrict__ Wc1, const float* __restrict__ bc1,
    const float* __restrict__ Wc2, const float* __restrict__ bc2,
    float* __restrict__ out)
{
    int bg = blockIdx.x;
    int j = threadIdx.x;
    float acc = 0.f;
    for (int p = 0; p < PP; ++p) {
        int c = bg * PP + p;
        acc += H[c * 64 + j] / (den[c] + 1e-6f);
    }
    float g = acc * (1.f / (float)PP);
    int m = j & 31;
    float a1 = bc1[m];
#pragma unroll
    for (int i = 0; i < 64; ++i) a1 = fmaf(rdlane(g, i), Wc1[i * 32 + m], a1);
    float c1 = fmaxf(a1, 0.f);
    int n = (j < NC) ? j : 0;
    float a2 = bc2[n];
#pragma unroll
    for (int i = 0; i < 32; ++i) a2 = fmaf(rdlane(c1, i), Wc2[i * NC + n], a2);
    if (j < NC) out[bg * NC + j] = a2;
}

// ---------------------------------------------------------------------------
extern "C" void kernel_launch(void* const* d_in, const int* in_sizes, int n_in,
                              void* d_out, int out_size, void* d_ws, size_t ws_size,
                              hipStream_t stream)
{
    const float* x      = (const float*)d_in[0];
    const int*   mapper = (const int*)d_in[1];
    const int*   batch  = (const int*)d_in[2];
    const int*   row    = (const int*)d_in[3];
    const int*   col    = (const int*)d_in[4];
    const float* attr   = (const float*)d_in[5];
    const float* W_in1  = (const float*)d_in[6];
    const float* b_in1  = (const float*)d_in[7];
    const float* W_in2  = (const float*)d_in[8];
    const float* b_in2  = (const float*)d_in[9];
    const float* W_pre1 = (const float*)d_in[10];
    const float* b_pre1 = (const float*)d_in[11];
    const float* W_pre2 = (const float*)d_in[12];
    const float* b_pre2 = (const float*)d_in[13];
    const float* W_post1= (const float*)d_in[14];
    const float* b_post1= (const float*)d_in[15];
    const float* W_post2= (const float*)d_in[16];
    const float* b_post2= (const float*)d_in[17];
    const float* W_K    = (const float*)d_in[18];
    const float* b_K    = (const float*)d_in[19];
    const float* W_V    = (const float*)d_in[20];
    const float* b_V    = (const float*)d_in[21];
    const float* alpha_beta = (const float*)d_in[22];
    const float* W_c1   = (const float*)d_in[23];
    const float* b_c1   = (const float*)d_in[24];
    const float* W_c2   = (const float*)d_in[25];
    const float* b_c2   = (const float*)d_in[26];

    float* ws = (float*)d_ws;
    float* u     = ws;                        // N*64
    float* KV    = u     + (size_t)NN * 64;   // N*128
    float* Qk    = KV    + (size_t)NN * 128;  // C*64
    float* eawS  = Qk    + (size_t)CC * 64;   // E (CSR order)
    float* Msb   = eawS  + (size_t)EE;        // C*4096
    float* Ksk   = Msb   + (size_t)CC * 4096; // C*64
    float* Krsum = Ksk   + (size_t)CC * 64;   // C*64
    float* Vsum  = Krsum + (size_t)CC * 64;   // C*64
    float* Lf    = Vsum  + (size_t)CC * 64;   // C
    // --- zeroed region (contiguous, 68608 floats = 67*256*4) ---
    float* H     = Lf    + (size_t)CC;        // C*64
    float* den   = H     + (size_t)CC * 64;   // C
    float* deg   = den   + (size_t)CC;        // C
    int*  rowcnt = (int*)(deg + (size_t)CC);  // C
    // --- end zeroed region ---
    int*  segoff = rowcnt + CC;               // C+1
    int*  rowptr = segoff + (CC + 1);         // C+1
    int*  rowfill= rowptr + (CC + 1);         // C
    int*  colS   = rowfill + CC;              // E (CSR order)

    k_zero<<<67, 256, 0, stream>>>(H);
    k_prep1<<<EE / 256, 256, 0, stream>>>(row, attr, deg, rowcnt, EE);
    k_scan<<<1, 1024, 0, stream>>>(rowcnt, rowptr, rowfill, batch, segoff);
    k_prep2<<<EE / 256, 256, 0, stream>>>(row, col, attr, deg, rowfill, colS, eawS, EE);
    k_node<<<NN / 64, 256, 0, stream>>>(x, W_in1, b_in1, W_in2, b_in2,
                                        W_pre1, b_pre1, W_K, b_K, W_V, b_V, u, KV);
    k_msb<<<CC, 256, 0, stream>>>(u, KV, mapper, segoff,
                                  W_pre2, b_pre2, W_post1, b_post1,
                                  W_post2, b_post2,
                                  Msb, Qk, Ksk, Krsum, Vsum, Lf);
    k_edges<<<CC, 256, 0, stream>>>(Msb, Qk, Ksk, Krsum, Vsum, Lf, eawS, colS,
                                    rowptr, alpha_beta, H, den);
    k_final<<<BB, 64, 0, stream>>>(H, den, W_c1, b_c1, W_c2, b_c2, (float*)d_out);
}